// Round 11
// baseline (159.263 us; speedup 1.0000x reference)
//
#include <hip/hip_runtime.h>
#include <hip/hip_fp16.h>

#define NN 50000
#define NE 800000
#define NB 16384

#define NBKT 784          // buckets of 64 node ids (784*64 = 50176 >= NN)
#define BCAP 1280         // per-bucket capacity (mean 1020, +8 sigma)
#define CAPL 8            // LDS staging depth per bucket per binning block
#define P1B  256          // binning blocks (1/CU) -> mean 4 entries/bucket/block
#define GEMM_GCN_BLOCKS 784   // 784*64 = 50176 rows (last block guarded)
#define GEMM_DNN_BLOCKS 256   // 256*64 = 16384 rows

typedef unsigned int uint;
typedef unsigned short ushort;

__device__ __forceinline__ float h2f(ushort u) {
    return __half2float(__ushort_as_half(u));
}

// ---------------- zero the counters (runtime fill kernel is pathological) ------
__global__ void zero_kernel(int* __restrict__ p, int n)
{
    for (int i = threadIdx.x; i < n; i += 256) p[i] = 0;
}

// ---------------- fused dual binning: one pass over ei -------------------------
// entC = (r<<6)|(c&63) keyed by c>>6 ; entR = ((r&63)<<16)|c keyed by r>>6
__global__ __launch_bounds__(512) void binCR(const int* __restrict__ ei,
    uint* __restrict__ bufC, uint* __restrict__ bufR,
    int* __restrict__ gcurC, int* __restrict__ gcurR)
{
    __shared__ uint stC[NBKT * CAPL];           // 25 KiB
    __shared__ uint stR[NBKT * CAPL];           // 25 KiB
    __shared__ int lcC[NBKT], lcR[NBKT];
    const int tid = threadIdx.x;
    const int lane = tid & 63;
    const int wv = tid >> 6;                    // 0..7
    for (int i = tid; i < NBKT; i += 512) { lcC[i] = 0; lcR[i] = 0; }
    __syncthreads();
    const int per = (NE + P1B - 1) / P1B;
    const int lo = blockIdx.x * per;
    const int hi = (lo + per < NE) ? lo + per : NE;
    for (int e = lo + tid; e < hi; e += 512) {
        int r = ei[e], c = ei[NE + e];
        uint entC = ((uint)r << 6) | (uint)(c & 63);
        int b = c >> 6;
        int pos = atomicAdd(&lcC[b], 1);
        if (pos < CAPL) stC[b * CAPL + pos] = entC;
        else { int gp = atomicAdd(&gcurC[b], 1); bufC[(size_t)b * BCAP + gp] = entC; }
        uint entR = ((uint)(r & 63) << 16) | (uint)c;
        int rb = r >> 6;
        int pos2 = atomicAdd(&lcR[rb], 1);
        if (pos2 < CAPL) stR[rb * CAPL + pos2] = entR;
        else { int gp = atomicAdd(&gcurR[rb], 1); bufR[(size_t)rb * BCAP + gp] = entR; }
    }
    __syncthreads();
    // coalesced flush: 8 buckets per wave iteration, 8 lanes per bucket
    for (int base = wv * 8; base < NBKT; base += 64) {
        int wb = base + (lane >> 3);            // base<=776 -> wb<=783 always valid
        int idx = lane & 7;
        int n = lcC[wb]; if (n > CAPL) n = CAPL;
        int gb = 0;
        if (idx == 0 && n > 0) gb = atomicAdd(&gcurC[wb], n);
        gb = __shfl(gb, lane & 56);
        if (idx < n) bufC[(size_t)wb * BCAP + gb + idx] = stC[wb * CAPL + idx];
        int n2 = lcR[wb]; if (n2 > CAPL) n2 = CAPL;
        int gb2 = 0;
        if (idx == 0 && n2 > 0) gb2 = atomicAdd(&gcurR[wb], n2);
        gb2 = __shfl(gb2, lane & 56);
        if (idx < n2) bufR[(size_t)wb * BCAP + gb2 + idx] = stR[wb * CAPL + idx];
    }
}

// ---------------- per-bucket in-degree histogram -> dis, cnth ------------------
__global__ __launch_bounds__(256) void cnt_dis(const uint* __restrict__ bufC,
    const int* __restrict__ gcurC, float* __restrict__ dis,
    int* __restrict__ cnth)
{
    __shared__ int hist[64];
    const int tid = threadIdx.x, bb = blockIdx.x;
    if (tid < 64) hist[tid] = 0;
    __syncthreads();
    const int n = gcurC[bb];
    const uint* src = bufC + (size_t)bb * BCAP;
    for (int i = tid; i < n; i += 256) atomicAdd(&hist[src[i] & 63], 1);
    __syncthreads();
    if (tid < 64) {
        int c = bb * 64 + tid;
        cnth[bb * 64 + tid] = hist[tid];
        if (c < NN) dis[c] = rsqrtf((float)hist[tid] + 1.0f);
    }
}

// ---------------- fused GEMMs, lane = output column ----------------------------
// Block = 64 rows staged in LDS (coalesced float4). Wave = 16 rows x 64 cols,
// acc[16]. W read as lane-contiguous vector loads (L1-resident panel).
// Blocks [0,784) = GCN1 (K=64, fp16-out, dis-scaled); [784,1040) = DNN (K=256).
__global__ __launch_bounds__(256) void gemm_both(
    const float* __restrict__ X2, const float* __restrict__ W1,
    const float* __restrict__ dis, ushort* __restrict__ Hh,
    const float* __restrict__ X1, const float* __restrict__ Wd,
    float* __restrict__ H)
{
    __shared__ float4 xs[64 * 16];              // 16 KiB: 64 rows x 64 k-floats
    const int tid = threadIdx.x;
    const int lane = tid & 63;
    const int wv = __builtin_amdgcn_readfirstlane(tid >> 6);
    float acc[16];
#pragma unroll
    for (int r = 0; r < 16; ++r) acc[r] = 0.f;

    if (blockIdx.x < GEMM_GCN_BLOCKS) {
        // ---- GCN1: h1h = fp16(dis[row] * (x2 @ g1W)), K = 64 ----
        const int row0 = blockIdx.x * 64;
        const float4* xsrc = reinterpret_cast<const float4*>(X2 + (size_t)row0 * 64);
        if (row0 + 64 <= NN) {
            for (int i = tid; i < 1024; i += 256) xs[i] = xsrc[i];
        } else {                                // last block: guard OOB rows
            for (int i = tid; i < 1024; i += 256)
                xs[i] = (row0 + (i >> 4) < NN) ? xsrc[i]
                                               : make_float4(0.f, 0.f, 0.f, 0.f);
        }
        __syncthreads();
#pragma unroll 1
        for (int k4 = 0; k4 < 16; ++k4) {
            const float* wb = W1 + (size_t)(k4 * 4) * 64;
            float w0 = wb[lane];
            float w1 = wb[64 + lane];
            float w2 = wb[128 + lane];
            float w3 = wb[192 + lane];
#pragma unroll
            for (int r = 0; r < 16; ++r) {
                float4 xv = xs[(wv * 16 + r) * 16 + k4];
                acc[r] = fmaf(xv.w, w3, fmaf(xv.z, w2,
                         fmaf(xv.y, w1, fmaf(xv.x, w0, acc[r]))));
            }
        }
#pragma unroll
        for (int r = 0; r < 16; ++r) {
            int row = row0 + wv * 16 + r;
            if (row < NN) {
                float d = dis[row];
                Hh[(size_t)row * 64 + lane] =
                    __half_as_ushort(__float2half_rn(d * acc[r]));
            }
        }
    } else {
        // ---- DNN: hdnn = x1 @ dnnW, K = 256 in 4 chunks of 64 ----
        const int row0 = (blockIdx.x - GEMM_GCN_BLOCKS) * 64;
        const float4* xsrc = reinterpret_cast<const float4*>(X1 + (size_t)row0 * 256);
#pragma unroll 1
        for (int chunk = 0; chunk < 4; ++chunk) {
            if (chunk) __syncthreads();         // xs reuse across chunks
            for (int i = tid; i < 1024; i += 256) {
                int r = i >> 4, k4 = i & 15;    // 64 float4 per row
                xs[i] = xsrc[r * 64 + chunk * 16 + k4];
            }
            __syncthreads();
#pragma unroll 1
            for (int k4 = 0; k4 < 16; ++k4) {
                const float* wb = Wd + (size_t)(chunk * 64 + k4 * 4) * 64;
                float w0 = wb[lane];
                float w1 = wb[64 + lane];
                float w2 = wb[128 + lane];
                float w3 = wb[192 + lane];
#pragma unroll
                for (int r = 0; r < 16; ++r) {
                    float4 xv = xs[(wv * 16 + r) * 16 + k4];
                    acc[r] = fmaf(xv.w, w3, fmaf(xv.z, w2,
                             fmaf(xv.y, w1, fmaf(xv.x, w0, acc[r]))));
                }
            }
        }
#pragma unroll
        for (int r = 0; r < 16; ++r) {
            int row = row0 + wv * 16 + r;
            H[(size_t)row * 64 + lane] = acc[r];
        }
    }
}

// ---------------- BN stats: column sum / sumsq over the batch -------------------
__global__ __launch_bounds__(256) void bn_stats(const float* __restrict__ H,
    float* __restrict__ bnsum, float* __restrict__ bnsumsq)
{
    const int tid = threadIdx.x;
    const int col = tid & 63, rg = tid >> 6;
    float s = 0.f, q = 0.f;
    for (int row = blockIdx.x * 4 + rg; row < NB; row += gridDim.x * 4) {
        float v = H[(size_t)row * 64 + col];
        s += v; q += v * v;
    }
    __shared__ float rs[4][64], rq[4][64];
    rs[rg][col] = s; rq[rg][col] = q;
    __syncthreads();
    if (rg == 0) {
        atomicAdd(&bnsum[col],  rs[0][col] + rs[1][col] + rs[2][col] + rs[3][col]);
        atomicAdd(&bnsumsq[col], rq[0][col] + rq[1][col] + rq[2][col] + rq[3][col]);
    }
}

// ---------------- gather + fused wraw + node epilogue --------------------------
// w[r&63] = sum dis[c] over out-edges of r (row-bucket bb) ; then per node c:
// g_c = dis_c*(sum_in h1d_r + h1d_c) + b1 ; coef_c = dis_c*w_c + dis_c^2
__global__ __launch_bounds__(512) void gather_pass(const uint* __restrict__ bufC,
    const int* __restrict__ gcurC, const int* __restrict__ cnth,
    const uint* __restrict__ bufR, const int* __restrict__ gcurR,
    const float* __restrict__ dis, const ushort* __restrict__ hs,
    const float* __restrict__ b1, float* __restrict__ svec)
{
    __shared__ int sorted[BCAP];
    __shared__ int cntS[64], offsS[64], curS[64];
    __shared__ float w[64];
    __shared__ float red[8][64];
    const int tid = threadIdx.x;
    const int lane = tid & 63;
    const int wv = __builtin_amdgcn_readfirstlane(tid >> 6);   // 0..7
    const int bb = blockIdx.x;
    if (tid < 64) {                              // wave 0: load hist + 64-wide scan
        w[tid] = 0.f;
        int v = cnth[bb * 64 + tid];
        cntS[tid] = v;
        int s = v;
#pragma unroll
        for (int o = 1; o < 64; o <<= 1) {
            int u = __shfl_up(s, o);
            if (lane >= o) s += u;
        }
        offsS[tid] = s - v;
        curS[tid] = s - v;
    }
    __syncthreads();
    // wraw accumulation from the row-bucket (dis is a 200 KB L2-resident table)
    const int n2 = gcurR[bb];
    const uint* srcR = bufR + (size_t)bb * BCAP;
    for (int i = tid; i < n2; i += 512) {
        uint e = srcR[i];
        atomicAdd(&w[e >> 16], dis[e & 0xffffu]);
    }
    // LDS counting-sort scatter of the col-bucket
    const int n = gcurC[bb];
    const uint* src = bufC + (size_t)bb * BCAP;
    for (int i = tid; i < n; i += 512) {
        uint e = src[i];
        int p = atomicAdd(&curS[e & 63u], 1);
        sorted[p] = (int)(e >> 6);
    }
    __syncthreads();
    // each wave: 8 consecutive nodes, register accumulation, 8-deep load ILP
    float sacc = 0.f;
    const float bl = b1[lane];
#pragma unroll 1
    for (int t = 0; t < 8; ++t) {
        const int nd = wv * 8 + t;
        const int lo = offsS[nd], hi2 = lo + cntS[nd];
        float acc = 0.f;
        int e = lo;
        for (; e + 8 <= hi2; e += 8) {
            int r0 = sorted[e],     r1 = sorted[e + 1];
            int r2 = sorted[e + 2], r3 = sorted[e + 3];
            int r4 = sorted[e + 4], r5 = sorted[e + 5];
            int r6 = sorted[e + 6], r7 = sorted[e + 7];
            ushort u0 = hs[(size_t)r0 * 64 + lane];
            ushort u1 = hs[(size_t)r1 * 64 + lane];
            ushort u2 = hs[(size_t)r2 * 64 + lane];
            ushort u3 = hs[(size_t)r3 * 64 + lane];
            ushort u4 = hs[(size_t)r4 * 64 + lane];
            ushort u5 = hs[(size_t)r5 * 64 + lane];
            ushort u6 = hs[(size_t)r6 * 64 + lane];
            ushort u7 = hs[(size_t)r7 * 64 + lane];
            acc += ((h2f(u0) + h2f(u1)) + (h2f(u2) + h2f(u3))) +
                   ((h2f(u4) + h2f(u5)) + (h2f(u6) + h2f(u7)));
        }
        for (; e + 2 <= hi2; e += 2) {
            ushort u0 = hs[(size_t)sorted[e] * 64 + lane];
            ushort u1 = hs[(size_t)sorted[e + 1] * 64 + lane];
            acc += h2f(u0) + h2f(u1);
        }
        if (e < hi2) acc += h2f(hs[(size_t)sorted[e] * 64 + lane]);
        const int c = bb * 64 + nd;
        if (c < NN) {
            float d = dis[c];
            float g = fmaf(d, acc + h2f(hs[(size_t)c * 64 + lane]), bl);
            float coef = fmaf(d, w[nd], d * d);
            sacc += coef * fmaxf(g, 0.f);
        }
    }
    red[wv][lane] = sacc;
    __syncthreads();
    if (wv == 0) {
        float s = ((red[0][lane] + red[1][lane]) + (red[2][lane] + red[3][lane])) +
                  ((red[4][lane] + red[5][lane]) + (red[6][lane] + red[7][lane]));
        atomicAdd(&svec[lane], s);
    }
}

// ---------------- output + fused finalize --------------------------------------
__global__ __launch_bounds__(256) void out_final(const float* __restrict__ H,
    const float* __restrict__ bnsum, const float* __restrict__ bnsumsq,
    const float* __restrict__ gamma, const float* __restrict__ beta,
    const float* __restrict__ svec, const float* __restrict__ g2W,
    const float* __restrict__ g2b, const float* __restrict__ fc1W,
    const float* __restrict__ fc1b, const float* __restrict__ fc2W,
    const float* __restrict__ fc2b, float* __restrict__ out)
{
    __shared__ float scaleS[64], shiftS[64], vdnnS[64];
    __shared__ float consS;
    const int tid = threadIdx.x;
    const int lane = tid & 63;
    const int grp = tid >> 6;
    if (tid < 64) {                              // wave 0 computes finalize
        int j = tid;
        float mu = bnsum[j] * (1.0f / NB);
        float var = bnsumsq[j] * (1.0f / NB) - mu * mu;
        float sc = rsqrtf(var + 1e-5f) * gamma[j];
        scaleS[j] = sc;
        shiftS[j] = beta[j] - mu * sc;
        float ge = 0.f;
        for (int k = 0; k < 64; ++k) ge += svec[k] * g2W[k * 64 + j];
        ge = ge * (1.0f / NN) + g2b[j];
        float vd = 0.f, vg = 0.f;
        for (int k = 0; k < 64; ++k) {
            vd += fc1W[j * 64 + k] * fc2W[k];
            vg += fc1W[(64 + j) * 64 + k] * fc2W[k];
        }
        vdnnS[j] = vd;
        float part = ge * vg + fc1b[j] * fc2W[j];
#pragma unroll
        for (int o = 32; o > 0; o >>= 1) part += __shfl_down(part, o);
        if (j == 0) consS = part + fc2b[0];
    }
    __syncthreads();
    const float sc = scaleS[lane], sh = shiftS[lane], vd = vdnnS[lane];
    const float C = consS;
#pragma unroll 1
    for (int t = 0; t < 8; ++t) {
        int i = blockIdx.x * 32 + grp * 8 + t;
        float x = H[(size_t)i * 64 + lane] * sc + sh;
        x = fmaxf(x, 0.f) * vd;
#pragma unroll
        for (int o = 32; o > 0; o >>= 1) x += __shfl_down(x, o);
        if (lane == 0) out[i] = x + C;
    }
}

extern "C" void kernel_launch(void* const* d_in, const int* in_sizes, int n_in,
                              void* d_out, int out_size, void* d_ws, size_t ws_size,
                              hipStream_t stream)
{
    const float* x1    = (const float*)d_in[0];
    const float* x2    = (const float*)d_in[1];
    const int*   ei    = (const int*)d_in[2];
    const float* dnnW  = (const float*)d_in[3];
    // d_in[4] = dnn_b: cancels inside BatchNorm, unused
    const float* gamma = (const float*)d_in[5];
    const float* beta  = (const float*)d_in[6];
    const float* g1W   = (const float*)d_in[7];
    const float* g1b   = (const float*)d_in[8];
    const float* g2W   = (const float*)d_in[9];
    const float* g2b   = (const float*)d_in[10];
    const float* fc1W  = (const float*)d_in[11];
    const float* fc1b  = (const float*)d_in[12];
    const float* fc2W  = (const float*)d_in[13];
    const float* fc2b  = (const float*)d_in[14];

    float* ws      = (float*)d_ws;
    ushort* h1h    = (ushort*)ws;                 // 50176*64 ushorts = 1,605,632 f
    float* hdnn    = ws + 1605632;                // 1,048,576 f
    float* dis     = hdnn + 1048576;              // 50,176 f
    int*   cnth    = (int*)(dis + 50176 + 25088); // 50,176 i (keeps old layout)
    uint*  bufC    = (uint*)(cnth + 50176);       // 784*1280 = 1,003,520
    uint*  bufR    = bufC + NBKT * BCAP;          // 1,003,520
    int*   gcurC   = (int*)(bufR + NBKT * BCAP);  // 784   <- zero region start
    int*   gcurR   = gcurC + NBKT;                // 784
    float* bnsum   = (float*)(gcurR + NBKT);      // 64
    float* bnsumsq = bnsum + 64;                  // 64
    float* svec    = bnsumsq + 64;                // 64    <- zero region end (1760)

    zero_kernel<<<1, 256, 0, stream>>>(gcurC, NBKT * 2 + 192);

    binCR<<<P1B, 512, 0, stream>>>(ei, bufC, bufR, gcurC, gcurR);
    cnt_dis<<<NBKT, 256, 0, stream>>>(bufC, gcurC, dis, cnth);
    gemm_both<<<GEMM_GCN_BLOCKS + GEMM_DNN_BLOCKS, 256, 0, stream>>>(
        x2, g1W, dis, h1h, x1, dnnW, hdnn);
    gather_pass<<<NBKT, 512, 0, stream>>>(bufC, gcurC, cnth, bufR, gcurR,
                                          dis, h1h, g1b, svec);
    bn_stats<<<256, 256, 0, stream>>>(hdnn, bnsum, bnsumsq);
    out_final<<<512, 256, 0, stream>>>(hdnn, bnsum, bnsumsq, gamma, beta, svec,
                                       g2W, g2b, fc1W, fc1b, fc2W, fc2b,
                                       (float*)d_out);
}

// Round 12
// 145.651 us; speedup vs baseline: 1.0935x; 1.0935x over previous
//
#include <hip/hip_runtime.h>
#include <hip/hip_fp16.h>

#define NN 50000
#define NE 800000
#define NB 16384

#define NBKT 784          // buckets of 64 node ids (784*64 = 50176 >= NN)
#define BCAP 1280         // per-bucket capacity (mean 1020, +8 sigma)
#define CAPL 8            // LDS staging depth per bucket per binning block
#define P1B  256          // binning blocks (1/CU) -> mean 4 entries/bucket/block
#define GCN_BLOCKS 1568   // 1568*4 waves = 6272 tasks = 784 rowg x 8 colg
#define DNN_BLOCKS 512    // 512*4  waves = 2048 tasks = 256 rowg x 8 colg

typedef unsigned int uint;
typedef unsigned short ushort;

__device__ __forceinline__ uint pack2h(float a, float b) {
    return (uint)__half_as_ushort(__float2half_rn(a)) |
           ((uint)__half_as_ushort(__float2half_rn(b)) << 16);
}
__device__ __forceinline__ float h2f(ushort u) {
    return __half2float(__ushort_as_half(u));
}

// ---------------- zero the counters (runtime fill kernel is pathological) ------
__global__ void zero_kernel(int* __restrict__ p, int n)
{
    for (int i = threadIdx.x; i < n; i += 256) p[i] = 0;
}

// ---------------- fused dual binning: one pass over ei -------------------------
// entC = (r<<6)|(c&63) keyed by c>>6 ; entR = ((r&63)<<16)|c keyed by r>>6
__global__ __launch_bounds__(512) void binCR(const int* __restrict__ ei,
    uint* __restrict__ bufC, uint* __restrict__ bufR,
    int* __restrict__ gcurC, int* __restrict__ gcurR)
{
    __shared__ uint stC[NBKT * CAPL];           // 25 KiB
    __shared__ uint stR[NBKT * CAPL];           // 25 KiB
    __shared__ int lcC[NBKT], lcR[NBKT];
    const int tid = threadIdx.x;
    const int lane = tid & 63;
    const int wv = tid >> 6;                    // 0..7
    for (int i = tid; i < NBKT; i += 512) { lcC[i] = 0; lcR[i] = 0; }
    __syncthreads();
    const int per = (NE + P1B - 1) / P1B;
    const int lo = blockIdx.x * per;
    const int hi = (lo + per < NE) ? lo + per : NE;
    for (int e = lo + tid; e < hi; e += 512) {
        int r = ei[e], c = ei[NE + e];
        uint entC = ((uint)r << 6) | (uint)(c & 63);
        int b = c >> 6;
        int pos = atomicAdd(&lcC[b], 1);
        if (pos < CAPL) stC[b * CAPL + pos] = entC;
        else { int gp = atomicAdd(&gcurC[b], 1); bufC[(size_t)b * BCAP + gp] = entC; }
        uint entR = ((uint)(r & 63) << 16) | (uint)c;
        int rb = r >> 6;
        int pos2 = atomicAdd(&lcR[rb], 1);
        if (pos2 < CAPL) stR[rb * CAPL + pos2] = entR;
        else { int gp = atomicAdd(&gcurR[rb], 1); bufR[(size_t)rb * BCAP + gp] = entR; }
    }
    __syncthreads();
    // coalesced flush: 8 buckets per wave iteration, 8 lanes per bucket
    for (int base = wv * 8; base < NBKT; base += 64) {
        int wb = base + (lane >> 3);            // base<=776 -> wb<=783 always valid
        int idx = lane & 7;
        int n = lcC[wb]; if (n > CAPL) n = CAPL;
        int gb = 0;
        if (idx == 0 && n > 0) gb = atomicAdd(&gcurC[wb], n);
        gb = __shfl(gb, lane & 56);
        if (idx < n) bufC[(size_t)wb * BCAP + gb + idx] = stC[wb * CAPL + idx];
        int n2 = lcR[wb]; if (n2 > CAPL) n2 = CAPL;
        int gb2 = 0;
        if (idx == 0 && n2 > 0) gb2 = atomicAdd(&gcurR[wb], n2);
        gb2 = __shfl(gb2, lane & 56);
        if (idx < n2) bufR[(size_t)wb * BCAP + gb2 + idx] = stR[wb * CAPL + idx];
    }
}

// ---------------- per-bucket in-degree histogram -> dis, cnth ------------------
__global__ __launch_bounds__(256) void cnt_dis(const uint* __restrict__ bufC,
    const int* __restrict__ gcurC, float* __restrict__ dis,
    int* __restrict__ cnth)
{
    __shared__ int hist[64];
    const int tid = threadIdx.x, bb = blockIdx.x;
    if (tid < 64) hist[tid] = 0;
    __syncthreads();
    const int n = gcurC[bb];
    const uint* src = bufC + (size_t)bb * BCAP;
    for (int i = tid; i < n; i += 256) atomicAdd(&hist[src[i] & 63], 1);
    __syncthreads();
    if (tid < 64) {
        int c = bb * 64 + tid;
        cnth[bb * 64 + tid] = hist[tid];
        if (c < NN) dis[c] = rsqrtf((float)hist[tid] + 1.0f);
    }
}

// ---------------- fused GEMMs: blocks [0,1568) = GCN1, [1568,2080) = DNN -------
// Wave = 64 rows x 8 cols. K processed in chunks of 64: the lane's 16 float4
// X values are loaded into a named register block FIRST (16 loads in flight),
// then 512 fully-unrolled FMAs with wave-uniform W reads (s_load).
__global__ __launch_bounds__(256) void gemm_both(
    const float* __restrict__ X2, const float* __restrict__ W1,
    const float* __restrict__ dis, ushort* __restrict__ Hh,
    const float* __restrict__ X1, const float* __restrict__ Wd,
    float* __restrict__ H)
{
    const int tid = threadIdx.x;
    const int lane = tid & 63;
    const int wv = __builtin_amdgcn_readfirstlane(tid >> 6);
    float acc[8];
#pragma unroll
    for (int j = 0; j < 8; ++j) acc[j] = 0.f;
    if (blockIdx.x < GCN_BLOCKS) {
        // ---- GCN1: h1h = fp16(dis[row] * (x2 @ g1W)), K=64 ----
        const int task = blockIdx.x * 4 + wv;    // 0..6271
        const int rowg = task >> 3;              // 0..783
        const int c0 = (task & 7) * 8;
        const int row = rowg * 64 + lane;
        if (row >= NN) return;
        const float4* xr = reinterpret_cast<const float4*>(X2 + (size_t)row * 64);
        float4 xv[16];
#pragma unroll
        for (int i = 0; i < 16; ++i) xv[i] = xr[i];   // 16 loads in flight
#pragma unroll
        for (int k4 = 0; k4 < 16; ++k4) {
            const float* wr = W1 + (size_t)(k4 * 4) * 64 + c0;
#pragma unroll
            for (int j = 0; j < 8; ++j) {
                float a = acc[j];
                a = fmaf(xv[k4].x, wr[j],       a);
                a = fmaf(xv[k4].y, wr[64 + j],  a);
                a = fmaf(xv[k4].z, wr[128 + j], a);
                a = fmaf(xv[k4].w, wr[192 + j], a);
                acc[j] = a;
            }
        }
        const float d = dis[row];
        uint4 p;
        p.x = pack2h(d * acc[0], d * acc[1]);
        p.y = pack2h(d * acc[2], d * acc[3]);
        p.z = pack2h(d * acc[4], d * acc[5]);
        p.w = pack2h(d * acc[6], d * acc[7]);
        *reinterpret_cast<uint4*>(Hh + (size_t)row * 64 + c0) = p;
    } else {
        // ---- DNN: hdnn = x1 @ dnnW, K=256 in 4 chunks of 64 ----
        const int task = (blockIdx.x - GCN_BLOCKS) * 4 + wv;   // 0..2047
        const int rowg = task >> 3;              // 0..255
        const int c0 = (task & 7) * 8;
        const int row = rowg * 64 + lane;
        const float4* xr = reinterpret_cast<const float4*>(X1 + (size_t)row * 256);
#pragma unroll 1
        for (int chunk = 0; chunk < 4; ++chunk) {
            float4 xv[16];
#pragma unroll
            for (int i = 0; i < 16; ++i) xv[i] = xr[chunk * 16 + i];
#pragma unroll
            for (int k4 = 0; k4 < 16; ++k4) {
                const float* wr = Wd + (size_t)(chunk * 64 + k4 * 4) * 64 + c0;
#pragma unroll
                for (int j = 0; j < 8; ++j) {
                    float a = acc[j];
                    a = fmaf(xv[k4].x, wr[j],       a);
                    a = fmaf(xv[k4].y, wr[64 + j],  a);
                    a = fmaf(xv[k4].z, wr[128 + j], a);
                    a = fmaf(xv[k4].w, wr[192 + j], a);
                    acc[j] = a;
                }
            }
        }
        float4* hr = reinterpret_cast<float4*>(H + (size_t)row * 64 + c0);
        hr[0] = make_float4(acc[0], acc[1], acc[2], acc[3]);
        hr[1] = make_float4(acc[4], acc[5], acc[6], acc[7]);
    }
}

// ---------------- BN stats: column sum / sumsq over the batch -------------------
__global__ __launch_bounds__(256) void bn_stats(const float* __restrict__ H,
    float* __restrict__ bnsum, float* __restrict__ bnsumsq)
{
    const int tid = threadIdx.x;
    const int col = tid & 63, rg = tid >> 6;
    float s = 0.f, q = 0.f;
    for (int row = blockIdx.x * 4 + rg; row < NB; row += gridDim.x * 4) {
        float v = H[(size_t)row * 64 + col];
        s += v; q += v * v;
    }
    __shared__ float rs[4][64], rq[4][64];
    rs[rg][col] = s; rq[rg][col] = q;
    __syncthreads();
    if (rg == 0) {
        atomicAdd(&bnsum[col],  rs[0][col] + rs[1][col] + rs[2][col] + rs[3][col]);
        atomicAdd(&bnsumsq[col], rq[0][col] + rq[1][col] + rq[2][col] + rq[3][col]);
    }
}

// ---------------- gather + fused wraw + node epilogue --------------------------
// w[r&63] = sum dis[c] over out-edges of r (row-bucket bb) ; then per node c:
// g_c = dis_c*(sum_in h1d_r + h1d_c) + b1 ; coef_c = dis_c*w_c + dis_c^2
__global__ __launch_bounds__(512) void gather_pass(const uint* __restrict__ bufC,
    const int* __restrict__ gcurC, const int* __restrict__ cnth,
    const uint* __restrict__ bufR, const int* __restrict__ gcurR,
    const float* __restrict__ dis, const ushort* __restrict__ hs,
    const float* __restrict__ b1, float* __restrict__ svec)
{
    __shared__ int sorted[BCAP];
    __shared__ int cntS[64], offsS[64], curS[64];
    __shared__ float w[64];
    __shared__ float red[8][64];
    const int tid = threadIdx.x;
    const int lane = tid & 63;
    const int wv = __builtin_amdgcn_readfirstlane(tid >> 6);   // 0..7
    const int bb = blockIdx.x;
    if (tid < 64) {                              // wave 0: load hist + 64-wide scan
        w[tid] = 0.f;
        int v = cnth[bb * 64 + tid];
        cntS[tid] = v;
        int s = v;
#pragma unroll
        for (int o = 1; o < 64; o <<= 1) {
            int u = __shfl_up(s, o);
            if (lane >= o) s += u;
        }
        offsS[tid] = s - v;
        curS[tid] = s - v;
    }
    __syncthreads();
    // wraw accumulation from the row-bucket (dis is a 200 KB L2-resident table)
    const int n2 = gcurR[bb];
    const uint* srcR = bufR + (size_t)bb * BCAP;
    for (int i = tid; i < n2; i += 512) {
        uint e = srcR[i];
        atomicAdd(&w[e >> 16], dis[e & 0xffffu]);
    }
    // LDS counting-sort scatter of the col-bucket
    const int n = gcurC[bb];
    const uint* src = bufC + (size_t)bb * BCAP;
    for (int i = tid; i < n; i += 512) {
        uint e = src[i];
        int p = atomicAdd(&curS[e & 63u], 1);
        sorted[p] = (int)(e >> 6);
    }
    __syncthreads();
    // each wave: 8 consecutive nodes, register accumulation, 8-deep load ILP
    float sacc = 0.f;
    const float bl = b1[lane];
#pragma unroll 1
    for (int t = 0; t < 8; ++t) {
        const int nd = wv * 8 + t;
        const int lo = offsS[nd], hi2 = lo + cntS[nd];
        float acc = 0.f;
        int e = lo;
        for (; e + 8 <= hi2; e += 8) {
            int r0 = sorted[e],     r1 = sorted[e + 1];
            int r2 = sorted[e + 2], r3 = sorted[e + 3];
            int r4 = sorted[e + 4], r5 = sorted[e + 5];
            int r6 = sorted[e + 6], r7 = sorted[e + 7];
            ushort u0 = hs[(size_t)r0 * 64 + lane];
            ushort u1 = hs[(size_t)r1 * 64 + lane];
            ushort u2 = hs[(size_t)r2 * 64 + lane];
            ushort u3 = hs[(size_t)r3 * 64 + lane];
            ushort u4 = hs[(size_t)r4 * 64 + lane];
            ushort u5 = hs[(size_t)r5 * 64 + lane];
            ushort u6 = hs[(size_t)r6 * 64 + lane];
            ushort u7 = hs[(size_t)r7 * 64 + lane];
            acc += ((h2f(u0) + h2f(u1)) + (h2f(u2) + h2f(u3))) +
                   ((h2f(u4) + h2f(u5)) + (h2f(u6) + h2f(u7)));
        }
        for (; e + 2 <= hi2; e += 2) {
            ushort u0 = hs[(size_t)sorted[e] * 64 + lane];
            ushort u1 = hs[(size_t)sorted[e + 1] * 64 + lane];
            acc += h2f(u0) + h2f(u1);
        }
        if (e < hi2) acc += h2f(hs[(size_t)sorted[e] * 64 + lane]);
        const int c = bb * 64 + nd;
        if (c < NN) {
            float d = dis[c];
            float g = fmaf(d, acc + h2f(hs[(size_t)c * 64 + lane]), bl);
            float coef = fmaf(d, w[nd], d * d);
            sacc += coef * fmaxf(g, 0.f);
        }
    }
    red[wv][lane] = sacc;
    __syncthreads();
    if (wv == 0) {
        float s = ((red[0][lane] + red[1][lane]) + (red[2][lane] + red[3][lane])) +
                  ((red[4][lane] + red[5][lane]) + (red[6][lane] + red[7][lane]));
        atomicAdd(&svec[lane], s);
    }
}

// ---------------- output + fused finalize --------------------------------------
__global__ __launch_bounds__(256) void out_final(const float* __restrict__ H,
    const float* __restrict__ bnsum, const float* __restrict__ bnsumsq,
    const float* __restrict__ gamma, const float* __restrict__ beta,
    const float* __restrict__ svec, const float* __restrict__ g2W,
    const float* __restrict__ g2b, const float* __restrict__ fc1W,
    const float* __restrict__ fc1b, const float* __restrict__ fc2W,
    const float* __restrict__ fc2b, float* __restrict__ out)
{
    __shared__ float scaleS[64], shiftS[64], vdnnS[64];
    __shared__ float consS;
    const int tid = threadIdx.x;
    const int lane = tid & 63;
    const int grp = tid >> 6;
    if (tid < 64) {                              // wave 0 computes finalize
        int j = tid;
        float mu = bnsum[j] * (1.0f / NB);
        float var = bnsumsq[j] * (1.0f / NB) - mu * mu;
        float sc = rsqrtf(var + 1e-5f) * gamma[j];
        scaleS[j] = sc;
        shiftS[j] = beta[j] - mu * sc;
        float ge = 0.f;
        for (int k = 0; k < 64; ++k) ge += svec[k] * g2W[k * 64 + j];
        ge = ge * (1.0f / NN) + g2b[j];
        float vd = 0.f, vg = 0.f;
        for (int k = 0; k < 64; ++k) {
            vd += fc1W[j * 64 + k] * fc2W[k];
            vg += fc1W[(64 + j) * 64 + k] * fc2W[k];
        }
        vdnnS[j] = vd;
        float part = ge * vg + fc1b[j] * fc2W[j];
#pragma unroll
        for (int o = 32; o > 0; o >>= 1) part += __shfl_down(part, o);
        if (j == 0) consS = part + fc2b[0];
    }
    __syncthreads();
    const float sc = scaleS[lane], sh = shiftS[lane], vd = vdnnS[lane];
    const float C = consS;
#pragma unroll 1
    for (int t = 0; t < 8; ++t) {
        int i = blockIdx.x * 32 + grp * 8 + t;
        float x = H[(size_t)i * 64 + lane] * sc + sh;
        x = fmaxf(x, 0.f) * vd;
#pragma unroll
        for (int o = 32; o > 0; o >>= 1) x += __shfl_down(x, o);
        if (lane == 0) out[i] = x + C;
    }
}

extern "C" void kernel_launch(void* const* d_in, const int* in_sizes, int n_in,
                              void* d_out, int out_size, void* d_ws, size_t ws_size,
                              hipStream_t stream)
{
    const float* x1    = (const float*)d_in[0];
    const float* x2    = (const float*)d_in[1];
    const int*   ei    = (const int*)d_in[2];
    const float* dnnW  = (const float*)d_in[3];
    // d_in[4] = dnn_b: cancels inside BatchNorm, unused
    const float* gamma = (const float*)d_in[5];
    const float* beta  = (const float*)d_in[6];
    const float* g1W   = (const float*)d_in[7];
    const float* g1b   = (const float*)d_in[8];
    const float* g2W   = (const float*)d_in[9];
    const float* g2b   = (const float*)d_in[10];
    const float* fc1W  = (const float*)d_in[11];
    const float* fc1b  = (const float*)d_in[12];
    const float* fc2W  = (const float*)d_in[13];
    const float* fc2b  = (const float*)d_in[14];

    float* ws      = (float*)d_ws;
    ushort* h1h    = (ushort*)ws;                 // 50176*64 ushorts = 1,605,632 f
    float* hdnn    = ws + 1605632;                // 1,048,576 f
    float* dis     = hdnn + 1048576;              // 50,176 f
    int*   cnth    = (int*)(dis + 50176 + 25088); // 50,176 i (keeps old layout)
    uint*  bufC    = (uint*)(cnth + 50176);       // 784*1280 = 1,003,520
    uint*  bufR    = bufC + NBKT * BCAP;          // 1,003,520
    int*   gcurC   = (int*)(bufR + NBKT * BCAP);  // 784   <- zero region start
    int*   gcurR   = gcurC + NBKT;                // 784
    float* bnsum   = (float*)(gcurR + NBKT);      // 64
    float* bnsumsq = bnsum + 64;                  // 64
    float* svec    = bnsumsq + 64;                // 64    <- zero region end (1760)

    zero_kernel<<<1, 256, 0, stream>>>(gcurC, NBKT * 2 + 192);

    binCR<<<P1B, 512, 0, stream>>>(ei, bufC, bufR, gcurC, gcurR);
    cnt_dis<<<NBKT, 256, 0, stream>>>(bufC, gcurC, dis, cnth);
    gemm_both<<<GCN_BLOCKS + DNN_BLOCKS, 256, 0, stream>>>(
        x2, g1W, dis, h1h, x1, dnnW, hdnn);
    gather_pass<<<NBKT, 512, 0, stream>>>(bufC, gcurC, cnth, bufR, gcurR,
                                          dis, h1h, g1b, svec);
    bn_stats<<<256, 256, 0, stream>>>(hdnn, bnsum, bnsumsq);
    out_final<<<512, 256, 0, stream>>>(hdnn, bnsum, bnsumsq, gamma, beta, svec,
                                       g2W, g2b, fc1W, fc1b, fc2W, fc2b,
                                       (float*)d_out);
}

// Round 13
// 137.184 us; speedup vs baseline: 1.1609x; 1.0617x over previous
//
#include <hip/hip_runtime.h>
#include <hip/hip_fp16.h>

#define NN 50000
#define NE 800000
#define NB 16384

#define NBKT 784          // buckets of 64 node ids (784*64 = 50176 >= NN)
#define BCAP 1280         // per-bucket capacity (mean 1020, +8 sigma)
#define CAPL 8            // LDS staging depth per bucket per binning block
#define P1B  256          // binning blocks (1/CU) -> mean 4 entries/bucket/block
#define GEMM_GCN_BLOCKS 784   // 64 rows/block (last block guarded)
#define GEMM_DNN_BLOCKS 256   // 64 rows/block

typedef unsigned int uint;
typedef unsigned short ushort;

__device__ __forceinline__ uint pack2h(float a, float b) {
    return (uint)__half_as_ushort(__float2half_rn(a)) |
           ((uint)__half_as_ushort(__float2half_rn(b)) << 16);
}
__device__ __forceinline__ float h2f(ushort u) {
    return __half2float(__ushort_as_half(u));
}

// ---------------- zero the counters (runtime fill kernel is pathological) ------
__global__ void zero_kernel(int* __restrict__ p, int n)
{
    for (int i = threadIdx.x; i < n; i += 256) p[i] = 0;
}

// ---------------- fused dual binning: one pass over ei -------------------------
// entC = (r<<6)|(c&63) keyed by c>>6 ; entR = ((r&63)<<16)|c keyed by r>>6
__global__ __launch_bounds__(512) void binCR(const int* __restrict__ ei,
    uint* __restrict__ bufC, uint* __restrict__ bufR,
    int* __restrict__ gcurC, int* __restrict__ gcurR)
{
    __shared__ uint stC[NBKT * CAPL];           // 25 KiB
    __shared__ uint stR[NBKT * CAPL];           // 25 KiB
    __shared__ int lcC[NBKT], lcR[NBKT];
    const int tid = threadIdx.x;
    const int lane = tid & 63;
    const int wv = tid >> 6;                    // 0..7
    for (int i = tid; i < NBKT; i += 512) { lcC[i] = 0; lcR[i] = 0; }
    __syncthreads();
    const int per = (NE + P1B - 1) / P1B;
    const int lo = blockIdx.x * per;
    const int hi = (lo + per < NE) ? lo + per : NE;
    for (int e = lo + tid; e < hi; e += 512) {
        int r = ei[e], c = ei[NE + e];
        uint entC = ((uint)r << 6) | (uint)(c & 63);
        int b = c >> 6;
        int pos = atomicAdd(&lcC[b], 1);
        if (pos < CAPL) stC[b * CAPL + pos] = entC;
        else { int gp = atomicAdd(&gcurC[b], 1); bufC[(size_t)b * BCAP + gp] = entC; }
        uint entR = ((uint)(r & 63) << 16) | (uint)c;
        int rb = r >> 6;
        int pos2 = atomicAdd(&lcR[rb], 1);
        if (pos2 < CAPL) stR[rb * CAPL + pos2] = entR;
        else { int gp = atomicAdd(&gcurR[rb], 1); bufR[(size_t)rb * BCAP + gp] = entR; }
    }
    __syncthreads();
    // coalesced flush: 8 buckets per wave iteration, 8 lanes per bucket
    for (int base = wv * 8; base < NBKT; base += 64) {
        int wb = base + (lane >> 3);            // base<=776 -> wb<=783 always valid
        int idx = lane & 7;
        int n = lcC[wb]; if (n > CAPL) n = CAPL;
        int gb = 0;
        if (idx == 0 && n > 0) gb = atomicAdd(&gcurC[wb], n);
        gb = __shfl(gb, lane & 56);
        if (idx < n) bufC[(size_t)wb * BCAP + gb + idx] = stC[wb * CAPL + idx];
        int n2 = lcR[wb]; if (n2 > CAPL) n2 = CAPL;
        int gb2 = 0;
        if (idx == 0 && n2 > 0) gb2 = atomicAdd(&gcurR[wb], n2);
        gb2 = __shfl(gb2, lane & 56);
        if (idx < n2) bufR[(size_t)wb * BCAP + gb2 + idx] = stR[wb * CAPL + idx];
    }
}

// ---------------- per-bucket in-degree histogram -> dis, cnth ------------------
__global__ __launch_bounds__(256) void cnt_dis(const uint* __restrict__ bufC,
    const int* __restrict__ gcurC, float* __restrict__ dis,
    int* __restrict__ cnth)
{
    __shared__ int hist[64];
    const int tid = threadIdx.x, bb = blockIdx.x;
    if (tid < 64) hist[tid] = 0;
    __syncthreads();
    const int n = gcurC[bb];
    const uint* src = bufC + (size_t)bb * BCAP;
    for (int i = tid; i < n; i += 256) atomicAdd(&hist[src[i] & 63], 1);
    __syncthreads();
    if (tid < 64) {
        int c = bb * 64 + tid;
        cnth[bb * 64 + tid] = hist[tid];
        if (c < NN) dis[c] = rsqrtf((float)hist[tid] + 1.0f);
    }
}

// ---------------- fused GEMMs, LDS-staged X with +1 pad ------------------------
// Block = 64 rows. Staging: tid-linear coalesced global reads -> xs[64][65]
// (bank = (row+k)%32, 2-way = free). Compute: lane = row (conflict-free b32
// reads), wave wv owns cols [wv*16, wv*16+16), acc[16], W via wave-uniform
// s_load. Output transposed back through xs so global stores are coalesced.
// Blocks [0,784) = GCN1 (K=64, fp16-out, dis-scaled); [784,1040) = DNN (K=256).
__global__ __launch_bounds__(256) void gemm_both(
    const float* __restrict__ X2, const float* __restrict__ W1,
    const float* __restrict__ dis, ushort* __restrict__ Hh,
    const float* __restrict__ X1, const float* __restrict__ Wd,
    float* __restrict__ H)
{
    __shared__ float xs[64 * 65];               // 16.25 KiB
    const int tid = threadIdx.x;
    const int lane = tid & 63;
    const int wv = __builtin_amdgcn_readfirstlane(tid >> 6);   // 0..3
    const int c0 = wv * 16;
    float acc[16];
#pragma unroll
    for (int j = 0; j < 16; ++j) acc[j] = 0.f;

    if (blockIdx.x < GEMM_GCN_BLOCKS) {
        // ---- GCN1: h1h = fp16(dis[row] * (x2 @ g1W)), K = 64 ----
        const int row0 = blockIdx.x * 64;
        if (row0 + 64 <= NN) {
            for (int i = tid; i < 4096; i += 256) {
                int r = i >> 6, k = i & 63;
                xs[r * 65 + k] = X2[(size_t)(row0 + r) * 64 + k];
            }
        } else {
            for (int i = tid; i < 4096; i += 256) {
                int r = i >> 6, k = i & 63;
                xs[r * 65 + k] = (row0 + r < NN)
                               ? X2[(size_t)(row0 + r) * 64 + k] : 0.f;
            }
        }
        __syncthreads();
        const float* xrow = xs + lane * 65;
#pragma unroll
        for (int k4 = 0; k4 < 16; ++k4) {
            float x0 = xrow[4 * k4 + 0];
            float x1 = xrow[4 * k4 + 1];
            float x2 = xrow[4 * k4 + 2];
            float x3 = xrow[4 * k4 + 3];
            const float* wr = W1 + (size_t)(4 * k4) * 64 + c0;
#pragma unroll
            for (int j = 0; j < 16; ++j) {
                float a = acc[j];
                a = fmaf(x0, wr[j],       a);
                a = fmaf(x1, wr[64 + j],  a);
                a = fmaf(x2, wr[128 + j], a);
                a = fmaf(x3, wr[192 + j], a);
                acc[j] = a;
            }
        }
        __syncthreads();                         // xs reads done
#pragma unroll
        for (int j = 0; j < 16; ++j) xs[lane * 65 + c0 + j] = acc[j];
        __syncthreads();
        // coalesced fp16 store: tid-linear over 64 rows x 32 uint pairs
        for (int i = tid; i < 2048; i += 256) {
            int r = i >> 5, cp = (i & 31) * 2;
            int row = row0 + r;
            if (row < NN) {
                float d = dis[row];
                uint v = pack2h(d * xs[r * 65 + cp], d * xs[r * 65 + cp + 1]);
                *reinterpret_cast<uint*>(Hh + (size_t)row * 64 + cp) = v;
            }
        }
    } else {
        // ---- DNN: hdnn = x1 @ dnnW, K = 256 in 4 staged chunks of 64 ----
        const int row0 = (blockIdx.x - GEMM_GCN_BLOCKS) * 64;
#pragma unroll 1
        for (int chunk = 0; chunk < 4; ++chunk) {
            if (chunk) __syncthreads();
            for (int i = tid; i < 4096; i += 256) {
                int r = i >> 6, k = i & 63;
                xs[r * 65 + k] = X1[(size_t)(row0 + r) * 256 + chunk * 64 + k];
            }
            __syncthreads();
            const float* xrow = xs + lane * 65;
#pragma unroll
            for (int k4 = 0; k4 < 16; ++k4) {
                float x0 = xrow[4 * k4 + 0];
                float x1 = xrow[4 * k4 + 1];
                float x2 = xrow[4 * k4 + 2];
                float x3 = xrow[4 * k4 + 3];
                const float* wr = Wd + (size_t)(chunk * 64 + 4 * k4) * 64 + c0;
#pragma unroll
                for (int j = 0; j < 16; ++j) {
                    float a = acc[j];
                    a = fmaf(x0, wr[j],       a);
                    a = fmaf(x1, wr[64 + j],  a);
                    a = fmaf(x2, wr[128 + j], a);
                    a = fmaf(x3, wr[192 + j], a);
                    acc[j] = a;
                }
            }
        }
        __syncthreads();
#pragma unroll
        for (int j = 0; j < 16; ++j) xs[lane * 65 + c0 + j] = acc[j];
        __syncthreads();
        for (int i = tid; i < 4096; i += 256) {  // coalesced float store
            int r = i >> 6, c = i & 63;
            H[(size_t)(row0 + r) * 64 + c] = xs[r * 65 + c];
        }
    }
}

// ---------------- BN stats: column sum / sumsq over the batch -------------------
__global__ __launch_bounds__(256) void bn_stats(const float* __restrict__ H,
    float* __restrict__ bnsum, float* __restrict__ bnsumsq)
{
    const int tid = threadIdx.x;
    const int col = tid & 63, rg = tid >> 6;
    float s = 0.f, q = 0.f;
    for (int row = blockIdx.x * 4 + rg; row < NB; row += gridDim.x * 4) {
        float v = H[(size_t)row * 64 + col];
        s += v; q += v * v;
    }
    __shared__ float rs[4][64], rq[4][64];
    rs[rg][col] = s; rq[rg][col] = q;
    __syncthreads();
    if (rg == 0) {
        atomicAdd(&bnsum[col],  rs[0][col] + rs[1][col] + rs[2][col] + rs[3][col]);
        atomicAdd(&bnsumsq[col], rq[0][col] + rq[1][col] + rq[2][col] + rq[3][col]);
    }
}

// ---------------- gather + fused wraw + node epilogue --------------------------
// w[r&63] = sum dis[c] over out-edges of r (row-bucket bb) ; then per node c:
// g_c = dis_c*(sum_in h1d_r + h1d_c) + b1 ; coef_c = dis_c*w_c + dis_c^2
__global__ __launch_bounds__(512) void gather_pass(const uint* __restrict__ bufC,
    const int* __restrict__ gcurC, const int* __restrict__ cnth,
    const uint* __restrict__ bufR, const int* __restrict__ gcurR,
    const float* __restrict__ dis, const ushort* __restrict__ hs,
    const float* __restrict__ b1, float* __restrict__ svec)
{
    __shared__ int sorted[BCAP];
    __shared__ int cntS[64], offsS[64], curS[64];
    __shared__ float w[64];
    __shared__ float red[8][64];
    const int tid = threadIdx.x;
    const int lane = tid & 63;
    const int wv = __builtin_amdgcn_readfirstlane(tid >> 6);   // 0..7
    const int bb = blockIdx.x;
    if (tid < 64) {                              // wave 0: load hist + 64-wide scan
        w[tid] = 0.f;
        int v = cnth[bb * 64 + tid];
        cntS[tid] = v;
        int s = v;
#pragma unroll
        for (int o = 1; o < 64; o <<= 1) {
            int u = __shfl_up(s, o);
            if (lane >= o) s += u;
        }
        offsS[tid] = s - v;
        curS[tid] = s - v;
    }
    __syncthreads();
    // wraw accumulation from the row-bucket (dis is a 200 KB L2-resident table)
    const int n2 = gcurR[bb];
    const uint* srcR = bufR + (size_t)bb * BCAP;
    for (int i = tid; i < n2; i += 512) {
        uint e = srcR[i];
        atomicAdd(&w[e >> 16], dis[e & 0xffffu]);
    }
    // LDS counting-sort scatter of the col-bucket
    const int n = gcurC[bb];
    const uint* src = bufC + (size_t)bb * BCAP;
    for (int i = tid; i < n; i += 512) {
        uint e = src[i];
        int p = atomicAdd(&curS[e & 63u], 1);
        sorted[p] = (int)(e >> 6);
    }
    __syncthreads();
    // each wave: 8 consecutive nodes, register accumulation, 8-deep load ILP
    float sacc = 0.f;
    const float bl = b1[lane];
#pragma unroll 1
    for (int t = 0; t < 8; ++t) {
        const int nd = wv * 8 + t;
        const int lo = offsS[nd], hi2 = lo + cntS[nd];
        float acc = 0.f;
        int e = lo;
        for (; e + 8 <= hi2; e += 8) {
            int r0 = sorted[e],     r1 = sorted[e + 1];
            int r2 = sorted[e + 2], r3 = sorted[e + 3];
            int r4 = sorted[e + 4], r5 = sorted[e + 5];
            int r6 = sorted[e + 6], r7 = sorted[e + 7];
            ushort u0 = hs[(size_t)r0 * 64 + lane];
            ushort u1 = hs[(size_t)r1 * 64 + lane];
            ushort u2 = hs[(size_t)r2 * 64 + lane];
            ushort u3 = hs[(size_t)r3 * 64 + lane];
            ushort u4 = hs[(size_t)r4 * 64 + lane];
            ushort u5 = hs[(size_t)r5 * 64 + lane];
            ushort u6 = hs[(size_t)r6 * 64 + lane];
            ushort u7 = hs[(size_t)r7 * 64 + lane];
            acc += ((h2f(u0) + h2f(u1)) + (h2f(u2) + h2f(u3))) +
                   ((h2f(u4) + h2f(u5)) + (h2f(u6) + h2f(u7)));
        }
        for (; e + 2 <= hi2; e += 2) {
            ushort u0 = hs[(size_t)sorted[e] * 64 + lane];
            ushort u1 = hs[(size_t)sorted[e + 1] * 64 + lane];
            acc += h2f(u0) + h2f(u1);
        }
        if (e < hi2) acc += h2f(hs[(size_t)sorted[e] * 64 + lane]);
        const int c = bb * 64 + nd;
        if (c < NN) {
            float d = dis[c];
            float g = fmaf(d, acc + h2f(hs[(size_t)c * 64 + lane]), bl);
            float coef = fmaf(d, w[nd], d * d);
            sacc += coef * fmaxf(g, 0.f);
        }
    }
    red[wv][lane] = sacc;
    __syncthreads();
    if (wv == 0) {
        float s = ((red[0][lane] + red[1][lane]) + (red[2][lane] + red[3][lane])) +
                  ((red[4][lane] + red[5][lane]) + (red[6][lane] + red[7][lane]));
        atomicAdd(&svec[lane], s);
    }
}

// ---------------- output + fused finalize --------------------------------------
__global__ __launch_bounds__(256) void out_final(const float* __restrict__ H,
    const float* __restrict__ bnsum, const float* __restrict__ bnsumsq,
    const float* __restrict__ gamma, const float* __restrict__ beta,
    const float* __restrict__ svec, const float* __restrict__ g2W,
    const float* __restrict__ g2b, const float* __restrict__ fc1W,
    const float* __restrict__ fc1b, const float* __restrict__ fc2W,
    const float* __restrict__ fc2b, float* __restrict__ out)
{
    __shared__ float scaleS[64], shiftS[64], vdnnS[64];
    __shared__ float consS;
    const int tid = threadIdx.x;
    const int lane = tid & 63;
    const int grp = tid >> 6;
    if (tid < 64) {                              // wave 0 computes finalize
        int j = tid;
        float mu = bnsum[j] * (1.0f / NB);
        float var = bnsumsq[j] * (1.0f / NB) - mu * mu;
        float sc = rsqrtf(var + 1e-5f) * gamma[j];
        scaleS[j] = sc;
        shiftS[j] = beta[j] - mu * sc;
        float ge = 0.f;
        for (int k = 0; k < 64; ++k) ge += svec[k] * g2W[k * 64 + j];
        ge = ge * (1.0f / NN) + g2b[j];
        float vd = 0.f, vg = 0.f;
        for (int k = 0; k < 64; ++k) {
            vd += fc1W[j * 64 + k] * fc2W[k];
            vg += fc1W[(64 + j) * 64 + k] * fc2W[k];
        }
        vdnnS[j] = vd;
        float part = ge * vg + fc1b[j] * fc2W[j];
#pragma unroll
        for (int o = 32; o > 0; o >>= 1) part += __shfl_down(part, o);
        if (j == 0) consS = part + fc2b[0];
    }
    __syncthreads();
    const float sc = scaleS[lane], sh = shiftS[lane], vd = vdnnS[lane];
    const float C = consS;
#pragma unroll 1
    for (int t = 0; t < 8; ++t) {
        int i = blockIdx.x * 32 + grp * 8 + t;
        float x = H[(size_t)i * 64 + lane] * sc + sh;
        x = fmaxf(x, 0.f) * vd;
#pragma unroll
        for (int o = 32; o > 0; o >>= 1) x += __shfl_down(x, o);
        if (lane == 0) out[i] = x + C;
    }
}

extern "C" void kernel_launch(void* const* d_in, const int* in_sizes, int n_in,
                              void* d_out, int out_size, void* d_ws, size_t ws_size,
                              hipStream_t stream)
{
    const float* x1    = (const float*)d_in[0];
    const float* x2    = (const float*)d_in[1];
    const int*   ei    = (const int*)d_in[2];
    const float* dnnW  = (const float*)d_in[3];
    // d_in[4] = dnn_b: cancels inside BatchNorm, unused
    const float* gamma = (const float*)d_in[5];
    const float* beta  = (const float*)d_in[6];
    const float* g1W   = (const float*)d_in[7];
    const float* g1b   = (const float*)d_in[8];
    const float* g2W   = (const float*)d_in[9];
    const float* g2b   = (const float*)d_in[10];
    const float* fc1W  = (const float*)d_in[11];
    const float* fc1b  = (const float*)d_in[12];
    const float* fc2W  = (const float*)d_in[13];
    const float* fc2b  = (const float*)d_in[14];

    float* ws      = (float*)d_ws;
    ushort* h1h    = (ushort*)ws;                 // 50176*64 ushorts = 1,605,632 f
    float* hdnn    = ws + 1605632;                // 1,048,576 f
    float* dis     = hdnn + 1048576;              // 50,176 f
    int*   cnth    = (int*)(dis + 50176 + 25088); // 50,176 i (keeps old layout)
    uint*  bufC    = (uint*)(cnth + 50176);       // 784*1280 = 1,003,520
    uint*  bufR    = bufC + NBKT * BCAP;          // 1,003,520
    int*   gcurC   = (int*)(bufR + NBKT * BCAP);  // 784   <- zero region start
    int*   gcurR   = gcurC + NBKT;                // 784
    float* bnsum   = (float*)(gcurR + NBKT);      // 64
    float* bnsumsq = bnsum + 64;                  // 64
    float* svec    = bnsumsq + 64;                // 64    <- zero region end (1760)

    zero_kernel<<<1, 256, 0, stream>>>(gcurC, NBKT * 2 + 192);

    binCR<<<P1B, 512, 0, stream>>>(ei, bufC, bufR, gcurC, gcurR);
    cnt_dis<<<NBKT, 256, 0, stream>>>(bufC, gcurC, dis, cnth);
    gemm_both<<<GEMM_GCN_BLOCKS + GEMM_DNN_BLOCKS, 256, 0, stream>>>(
        x2, g1W, dis, h1h, x1, dnnW, hdnn);
    gather_pass<<<NBKT, 512, 0, stream>>>(bufC, gcurC, cnth, bufR, gcurR,
                                          dis, h1h, g1b, svec);
    bn_stats<<<256, 256, 0, stream>>>(hdnn, bnsum, bnsumsq);
    out_final<<<512, 256, 0, stream>>>(hdnn, bnsum, bnsumsq, gamma, beta, svec,
                                       g2W, g2b, fc1W, fc1b, fc2W, fc2b,
                                       (float*)d_out);
}